// Round 6
// baseline (347.938 us; speedup 1.0000x reference)
//
#include <hip/hip_runtime.h>
#include <hip/hip_bf16.h>

// GCN 7-layer forward on MI355X. R6:
//  - fused agg+GEMM block-tile kernel for agg-first layers (L2,L3,L5,L6):
//    64 nodes/block, gather->LDS(split-bf16, XOR-swizzled)->MFMA. Removes
//    ~100 MB of t-plane round trips + 4 dispatches.
//  - L1 GEMM reads in_feat fp32 directly (scale+split in registers);
//    split_feat kernel deleted (41 MB round trip).

#define IN_F 128
#define NSLICE 60
#define SHB 13          // 8192 nodes/shard, 32 KB LDS
#define NSHARD 5        // ceil(40000/8192)

typedef __attribute__((ext_vector_type(8))) short short8v;   // 8 bf16
typedef __attribute__((ext_vector_type(4))) float f32x4;
typedef __attribute__((ext_vector_type(8))) _Float16 half8v; // 16 B

static __device__ __forceinline__ unsigned short f2bf(float x) {
    unsigned u = __builtin_bit_cast(unsigned, x);
    unsigned r = (u + 0x7FFFu + ((u >> 16) & 1u)) >> 16;   // rn-even
    return (unsigned short)r;
}
static __device__ __forceinline__ float bf2f(unsigned short h) {
    unsigned u = ((unsigned)h) << 16;
    return __builtin_bit_cast(float, u);
}

// ---------------- LDS histogram: grid (NSLICE, NSHARD, 2) ----------------

__global__ __launch_bounds__(256) void hist2_kernel(const int* __restrict__ src,
                                                    const int* __restrict__ dst,
                                                    int* __restrict__ scratch, int E) {
    constexpr int SH = 1 << SHB;
    __shared__ int h[SH];
    const int t = threadIdx.x;
    const int b = blockIdx.x;            // edge slice
    const int s = blockIdx.y;            // node shard
    const int z = blockIdx.z;            // 0 = src (out-deg), 1 = dst (in-deg)
    const int* idx = z ? dst : src;
    for (int i = t; i < SH; i += 256) h[i] = 0;
    __syncthreads();
    const int per = (E + NSLICE - 1) / NSLICE;
    const int lo = b * per;
    const int hiE = min(lo + per, E);
    const int base = s << SHB;
    for (int e = lo + t; e < hiE; e += 256) {
        unsigned a = (unsigned)(idx[e] - base);
        if (a < (unsigned)SH) atomicAdd(&h[a], 1);
    }
    __syncthreads();
    int* so = scratch + ((size_t)((z * NSHARD + s) * NSLICE + b) << SHB);
    for (int i = t; i < SH; i += 256) so[i] = h[i];
}

__global__ void hist_reduce_kernel(const int* __restrict__ scratch,
                                   int* __restrict__ in_deg,
                                   float* __restrict__ out_nrm,
                                   float* __restrict__ in_nrm, int N) {
    constexpr int SH = 1 << SHB;
    int n = blockIdx.x * blockDim.x + threadIdx.x;
    if (n >= N) return;
    int s = n >> SHB;
    int i = n & (SH - 1);
    int od = 0, idg = 0;
    for (int b = 0; b < NSLICE; ++b) {
        od  += scratch[((size_t)((0 * NSHARD + s) * NSLICE + b) << SHB) + i];
        idg += scratch[((size_t)((1 * NSHARD + s) * NSLICE + b) << SHB) + i];
    }
    in_deg[n] = idg;
    out_nrm[n] = od  > 0 ? rsqrtf((float)od)  : 0.f;
    in_nrm[n]  = idg > 0 ? rsqrtf((float)idg) : 0.f;
}

// ---------------- multi-block exclusive scan of in_deg -> row_off ----------------

__global__ __launch_bounds__(256) void scan_blk_kernel(const int* __restrict__ deg,
                                                       int* __restrict__ blockSums, int N) {
    __shared__ int ws[4];
    const int t = threadIdx.x;
    const int base = blockIdx.x * 1024 + t * 4;
    int4 v = make_int4(0, 0, 0, 0);
    if (base + 3 < N) v = *reinterpret_cast<const int4*>(&deg[base]);
    else if (base < N) {
        v.x = deg[base];
        if (base + 1 < N) v.y = deg[base + 1];
        if (base + 2 < N) v.z = deg[base + 2];
    }
    int s = v.x + v.y + v.z + v.w;
#pragma unroll
    for (int off = 32; off > 0; off >>= 1) s += __shfl_down(s, off);
    if ((t & 63) == 0) ws[t >> 6] = s;
    __syncthreads();
    if (t == 0) blockSums[blockIdx.x] = ws[0] + ws[1] + ws[2] + ws[3];
}

__global__ __launch_bounds__(64) void scan_top_kernel(const int* __restrict__ blockSums,
                                                      int* __restrict__ blockOffs,
                                                      int* __restrict__ row_off, int NB, int N) {
    const int t = threadIdx.x;
    int orig = (t < NB) ? blockSums[t] : 0;
    int v = orig;
#pragma unroll
    for (int off = 1; off < 64; off <<= 1) {
        int u = __shfl_up(v, off);
        if (t >= off) v += u;
    }
    if (t < NB) blockOffs[t] = v - orig;
    if (t == 63) row_off[N] = v;
}

__global__ __launch_bounds__(256) void scan_fill_kernel(const int* __restrict__ deg,
                                                        const int* __restrict__ blockOffs,
                                                        int* __restrict__ row_off, int N) {
    __shared__ int wtot[4];
    const int t = threadIdx.x;
    const int lane = t & 63;
    const int wid = t >> 6;
    const int base = blockIdx.x * 1024 + t * 4;
    int4 v = make_int4(0, 0, 0, 0);
    if (base + 3 < N) v = *reinterpret_cast<const int4*>(&deg[base]);
    else if (base < N) {
        v.x = deg[base];
        if (base + 1 < N) v.y = deg[base + 1];
        if (base + 2 < N) v.z = deg[base + 2];
    }
    const int s = v.x + v.y + v.z + v.w;
    int incl = s;
#pragma unroll
    for (int off = 1; off < 64; off <<= 1) {
        int u = __shfl_up(incl, off);
        if (lane >= off) incl += u;
    }
    if (lane == 63) wtot[wid] = incl;
    __syncthreads();
    int pre = blockOffs[blockIdx.x] + incl - s;
    for (int i = 0; i < wid; ++i) pre += wtot[i];
    if (base < N) {
        int run = pre;
        row_off[base] = run; run += v.x;
        if (base + 1 < N) { row_off[base + 1] = run; run += v.y; }
        if (base + 2 < N) { row_off[base + 2] = run; run += v.z; }
        if (base + 3 < N) { row_off[base + 3] = run; }
    }
}

// per-(slice,node) dst counts -> global base positions
__global__ void slice_base_kernel(int* __restrict__ scratch,
                                  const int* __restrict__ row_off, int N) {
    constexpr int SH = 1 << SHB;
    int n = blockIdx.x * blockDim.x + threadIdx.x;
    if (n >= N) return;
    int s = n >> SHB;
    int i = n & (SH - 1);
    int run = row_off[n];
    for (int b = 0; b < NSLICE; ++b) {
        size_t off = ((size_t)((NSHARD + s) * NSLICE + b) << SHB) + i;
        int c = scratch[off];
        scratch[off] = run;
        run += c;
    }
}

// place edges using LDS cursors seeded from slice bases; no global atomics
__global__ __launch_bounds__(256) void fill2_kernel(const int* __restrict__ src,
                                                    const int* __restrict__ dst,
                                                    const int* __restrict__ scratch,
                                                    int* __restrict__ csr, int E) {
    constexpr int SH = 1 << SHB;
    __shared__ int cur[SH];
    const int t = threadIdx.x;
    const int b = blockIdx.x;   // slice
    const int s = blockIdx.y;   // shard
    const int* base = scratch + ((size_t)((NSHARD + s) * NSLICE + b) << SHB);
    for (int i = t; i < SH; i += 256) cur[i] = base[i];
    __syncthreads();
    const int per = (E + NSLICE - 1) / NSLICE;
    const int lo = b * per;
    const int hiE = min(lo + per, E);
    const int nb = s << SHB;
    for (int e = lo + t; e < hiE; e += 256) {
        unsigned a = (unsigned)(dst[e] - nb);
        if (a < (unsigned)SH) {
            int pos = atomicAdd(&cur[a], 1);
            csr[pos] = src[e];
        }
    }
}

// ---------------- weight split/transpose ----------------

struct WDesc { const float* w; unsigned short* th; unsigned short* tl; int K; int N; };
struct WPack { WDesc d[6]; };

__global__ __launch_bounds__(256) void split_w_kernel(WPack p) {
    WDesc d = p.d[blockIdx.x];
    int i = blockIdx.y * 256 + threadIdx.x;
    if (i >= d.K * d.N) return;
    int k = i / d.N, n = i - k * d.N;
    float v = d.w[i];
    unsigned short h = f2bf(v);
    d.th[(size_t)n * d.K + k] = h;
    d.tl[(size_t)n * d.K + k] = f2bf(v - bf2f(h));
}

// ---------------- L1 GEMM: fp32 input, scale+split in registers ----------------
// Y16 = (X * pre[row]) @ Wt^T, fp16 out. No epilogue norms.

template<int K, int NOUT>
__global__ __launch_bounds__(256) void gemm_mfma_f32(
    const float* __restrict__ X,
    const unsigned short* __restrict__ Bh, const unsigned short* __restrict__ Bl,
    const float* __restrict__ pre, _Float16* __restrict__ Y16, int M) {
    constexpr int NT = NOUT / 16;
    const int lane = threadIdx.x & 63;
    const int wv = threadIdx.x >> 6;
    const int r0 = blockIdx.x * 64 + wv * 16;
    const int arow = r0 + (lane & 15);
    const int kg = (lane >> 4) * 8;
    const float sc = pre[arow];

    f32x4 acc[NT];
#pragma unroll
    for (int n = 0; n < NT; ++n) acc[n] = (f32x4){0.f, 0.f, 0.f, 0.f};

    for (int kk = 0; kk < K; kk += 32) {
        const float* ap = &X[(size_t)arow * K + kk + kg];
        float4 v0 = *reinterpret_cast<const float4*>(ap);
        float4 v1 = *reinterpret_cast<const float4*>(ap + 4);
        float a[8] = {v0.x, v0.y, v0.z, v0.w, v1.x, v1.y, v1.z, v1.w};
        short8v a_h, a_l;
#pragma unroll
        for (int j = 0; j < 8; ++j) {
            float f = a[j] * sc;
            unsigned short hh = f2bf(f);
            a_h[j] = (short)hh;
            a_l[j] = (short)f2bf(f - bf2f(hh));
        }
#pragma unroll
        for (int n = 0; n < NT; ++n) {
            int col = n * 16 + (lane & 15);
            short8v b_h = *reinterpret_cast<const short8v*>(Bh + (size_t)col * K + kk + kg);
            short8v b_l = *reinterpret_cast<const short8v*>(Bl + (size_t)col * K + kk + kg);
            acc[n] = __builtin_amdgcn_mfma_f32_16x16x32_bf16(a_h, b_h, acc[n], 0, 0, 0);
            acc[n] = __builtin_amdgcn_mfma_f32_16x16x32_bf16(a_h, b_l, acc[n], 0, 0, 0);
            acc[n] = __builtin_amdgcn_mfma_f32_16x16x32_bf16(a_l, b_h, acc[n], 0, 0, 0);
        }
    }
    const int c0 = lane & 15;
    const int rr = r0 + (lane >> 4) * 4;
#pragma unroll
    for (int n = 0; n < NT; ++n) {
        const int col = n * 16 + c0;
#pragma unroll
        for (int j = 0; j < 4; ++j)
            Y16[(size_t)(rr + j) * NOUT + col] = (_Float16)acc[n][j];
    }
}

// ---------------- L4 GEMM: split-bf16 plane input, fp16 out ----------------

template<int K, int NOUT>
__global__ __launch_bounds__(256) void gemm_mfma(
    const unsigned short* __restrict__ Ah, const unsigned short* __restrict__ Al,
    const unsigned short* __restrict__ Bh, const unsigned short* __restrict__ Bl,
    _Float16* __restrict__ Y16, int M) {
    constexpr int NT = NOUT / 16;
    const int lane = threadIdx.x & 63;
    const int wv = threadIdx.x >> 6;
    const int r0 = blockIdx.x * 64 + wv * 16;
    const int arow = r0 + (lane & 15);
    const int kg = (lane >> 4) * 8;

    f32x4 acc[NT];
#pragma unroll
    for (int n = 0; n < NT; ++n) acc[n] = (f32x4){0.f, 0.f, 0.f, 0.f};

    for (int kk = 0; kk < K; kk += 32) {
        short8v a_h = *reinterpret_cast<const short8v*>(Ah + (size_t)arow * K + kk + kg);
        short8v a_l = *reinterpret_cast<const short8v*>(Al + (size_t)arow * K + kk + kg);
#pragma unroll
        for (int n = 0; n < NT; ++n) {
            int col = n * 16 + (lane & 15);
            short8v b_h = *reinterpret_cast<const short8v*>(Bh + (size_t)col * K + kk + kg);
            short8v b_l = *reinterpret_cast<const short8v*>(Bl + (size_t)col * K + kk + kg);
            acc[n] = __builtin_amdgcn_mfma_f32_16x16x32_bf16(a_h, b_h, acc[n], 0, 0, 0);
            acc[n] = __builtin_amdgcn_mfma_f32_16x16x32_bf16(a_h, b_l, acc[n], 0, 0, 0);
            acc[n] = __builtin_amdgcn_mfma_f32_16x16x32_bf16(a_l, b_h, acc[n], 0, 0, 0);
        }
    }
    const int c0 = lane & 15;
    const int rr = r0 + (lane >> 4) * 4;
#pragma unroll
    for (int n = 0; n < NT; ++n) {
        const int col = n * 16 + c0;
#pragma unroll
        for (int j = 0; j < 4; ++j)
            Y16[(size_t)(rr + j) * NOUT + col] = (_Float16)acc[n][j];
    }
}

// ---------------- fused agg+GEMM (agg-first layers) ----------------
// Block = 64 nodes. Phase 1: wave wv aggregates nodes wv*16..wv*16+15 from
// gathered fp16 rows, splits to bf16 hi/lo, stores to LDS (XOR-swizzled
// 16B groups). Phase 2: MFMA A-from-LDS, B-planes from global; epilogue
// relu(acc*r + bias)*s. OUTM: 0 = fp16 out, 1 = split-bf16 planes out.

template<int K, int NOUT, int OUTM>
__global__ __launch_bounds__(256) void fused_ag(
    const _Float16* __restrict__ X, const int* __restrict__ csr,
    const int* __restrict__ row_off,
    const unsigned short* __restrict__ Bh, const unsigned short* __restrict__ Bl,
    const float* __restrict__ r_nrm, const float* __restrict__ s_nrm,
    const float* __restrict__ bias,
    _Float16* __restrict__ Y16, unsigned short* __restrict__ Yh,
    unsigned short* __restrict__ Yl, int N) {
    constexpr int G = K / 8;       // 16B groups per row == lanes per edge row
    constexpr int LPE = G;
    constexpr int EPW = 64 / LPE;
    constexpr int NT = NOUT / 16;
    __shared__ unsigned short sAh[64 * K];
    __shared__ unsigned short sAl[64 * K];
    const int lane = threadIdx.x & 63;
    const int wv = threadIdx.x >> 6;
    const int g = lane / LPE;
    const int c = lane % LPE;
    const int nodeBase = blockIdx.x * 64 + wv * 16;

    // ---- phase 1: aggregate 16 nodes per wave ----
    for (int i = 0; i < 16; ++i) {
        const int node = nodeBase + i;
        if (node >= N) break;
        const int lo = row_off[node];
        const int hi = row_off[node + 1];
        float acc[8], acc2[8];
#pragma unroll
        for (int j = 0; j < 8; ++j) { acc[j] = 0.f; acc2[j] = 0.f; }
        int e = lo + g;
        for (; e + EPW < hi; e += 2 * EPW) {
            int s0 = csr[e];
            int s1 = csr[e + EPW];
            half8v x0 = *reinterpret_cast<const half8v*>(&X[(size_t)s0 * K + c * 8]);
            half8v x1 = *reinterpret_cast<const half8v*>(&X[(size_t)s1 * K + c * 8]);
#pragma unroll
            for (int j = 0; j < 8; ++j) { acc[j] += (float)x0[j]; acc2[j] += (float)x1[j]; }
        }
        if (e < hi) {
            int s0 = csr[e];
            half8v x0 = *reinterpret_cast<const half8v*>(&X[(size_t)s0 * K + c * 8]);
#pragma unroll
            for (int j = 0; j < 8; ++j) acc[j] += (float)x0[j];
        }
#pragma unroll
        for (int j = 0; j < 8; ++j) acc[j] += acc2[j];
#pragma unroll
        for (int m = LPE; m < 64; m <<= 1) {
#pragma unroll
            for (int j = 0; j < 8; ++j) acc[j] += __shfl_xor(acc[j], m);
        }
        if (lane < LPE) {
            const int row = wv * 16 + i;
            short8v hv, lv;
#pragma unroll
            for (int j = 0; j < 8; ++j) {
                unsigned short hh = f2bf(acc[j]);
                hv[j] = (short)hh;
                lv[j] = (short)f2bf(acc[j] - bf2f(hh));
            }
            const int grp = c ^ (row & (G - 1));
            *reinterpret_cast<short8v*>(&sAh[row * K + grp * 8]) = hv;
            *reinterpret_cast<short8v*>(&sAl[row * K + grp * 8]) = lv;
        }
    }
    __syncthreads();

    // ---- phase 2: MFMA from LDS ----
    const int arow = wv * 16 + (lane & 15);
    f32x4 oacc[NT];
#pragma unroll
    for (int n = 0; n < NT; ++n) oacc[n] = (f32x4){0.f, 0.f, 0.f, 0.f};

    for (int kk = 0; kk < K; kk += 32) {
        const int gidx = (kk >> 3) + (lane >> 4);
        const int grp = gidx ^ (arow & (G - 1));
        short8v a_h = *reinterpret_cast<const short8v*>(&sAh[arow * K + grp * 8]);
        short8v a_l = *reinterpret_cast<const short8v*>(&sAl[arow * K + grp * 8]);
        const int kg = (lane >> 4) * 8;
#pragma unroll
        for (int n = 0; n < NT; ++n) {
            int col = n * 16 + (lane & 15);
            short8v b_h = *reinterpret_cast<const short8v*>(Bh + (size_t)col * K + kk + kg);
            short8v b_l = *reinterpret_cast<const short8v*>(Bl + (size_t)col * K + kk + kg);
            oacc[n] = __builtin_amdgcn_mfma_f32_16x16x32_bf16(a_h, b_h, oacc[n], 0, 0, 0);
            oacc[n] = __builtin_amdgcn_mfma_f32_16x16x32_bf16(a_h, b_l, oacc[n], 0, 0, 0);
            oacc[n] = __builtin_amdgcn_mfma_f32_16x16x32_bf16(a_l, b_h, oacc[n], 0, 0, 0);
        }
    }

    const int c0 = lane & 15;
    const int rr = blockIdx.x * 64 + wv * 16 + (lane >> 4) * 4;
#pragma unroll
    for (int n = 0; n < NT; ++n) {
        const int col = n * 16 + c0;
        const float bcol = bias[col];
#pragma unroll
        for (int j = 0; j < 4; ++j) {
            const int row = rr + j;
            float y = fmaf(oacc[n][j], r_nrm[row], bcol);
            y = fmaxf(y, 0.f);
            y *= s_nrm[row];
            if (OUTM == 0) {
                Y16[(size_t)row * NOUT + col] = (_Float16)y;
            } else {
                unsigned short h = f2bf(y);
                Yh[(size_t)row * NOUT + col] = h;
                Yl[(size_t)row * NOUT + col] = f2bf(y - bf2f(h));
            }
        }
    }
}

// ---------------- standalone agg (mult-first layers L1,L4) ----------------

template<int F>
__global__ __launch_bounds__(256) void agg_h16(
    const _Float16* __restrict__ X, const int* __restrict__ csr,
    const int* __restrict__ row_off, const float* __restrict__ r_nrm,
    const float* __restrict__ s_nrm, const float* __restrict__ bias,
    _Float16* __restrict__ Y16, int N) {
    constexpr int LPE = F / 8;
    constexpr int EPW = 64 / LPE;
    const int lane = threadIdx.x & 63;
    const int node = blockIdx.x * (blockDim.x >> 6) + (threadIdx.x >> 6);
    if (node >= N) return;
    const int g = lane / LPE;
    const int c = lane % LPE;
    const int lo = row_off[node];
    const int hi = row_off[node + 1];
    float acc[8], acc2[8];
#pragma unroll
    for (int j = 0; j < 8; ++j) { acc[j] = 0.f; acc2[j] = 0.f; }
    int e = lo + g;
    for (; e + EPW < hi; e += 2 * EPW) {
        int s0 = csr[e];
        int s1 = csr[e + EPW];
        half8v x0 = *reinterpret_cast<const half8v*>(&X[(size_t)s0 * F + c * 8]);
        half8v x1 = *reinterpret_cast<const half8v*>(&X[(size_t)s1 * F + c * 8]);
#pragma unroll
        for (int j = 0; j < 8; ++j) { acc[j] += (float)x0[j]; acc2[j] += (float)x1[j]; }
    }
    if (e < hi) {
        int s0 = csr[e];
        half8v x0 = *reinterpret_cast<const half8v*>(&X[(size_t)s0 * F + c * 8]);
#pragma unroll
        for (int j = 0; j < 8; ++j) acc[j] += (float)x0[j];
    }
#pragma unroll
    for (int j = 0; j < 8; ++j) acc[j] += acc2[j];
#pragma unroll
    for (int m = LPE; m < 64; m <<= 1) {
#pragma unroll
        for (int j = 0; j < 8; ++j) acc[j] += __shfl_xor(acc[j], m);
    }
    if (lane < LPE) {
        float rn = r_nrm[node];
        float sn = s_nrm[node];
        half8v o;
#pragma unroll
        for (int j = 0; j < 8; ++j) {
            float y = fmaf(acc[j], rn, bias[lane * 8 + j]);
            y = fmaxf(y, 0.f) * sn;
            o[j] = (_Float16)y;
        }
        *reinterpret_cast<half8v*>(&Y16[(size_t)node * F + lane * 8]) = o;
    }
}

// ---------------- layer 7 ----------------

__global__ __launch_bounds__(256) void gemv64_kernel(const _Float16* __restrict__ X,
                                                     const float* __restrict__ W,
                                                     float* __restrict__ Y, int M) {
    const int lane = threadIdx.x & 63;
    const int m = blockIdx.x * (blockDim.x >> 6) + (threadIdx.x >> 6);
    if (m >= M) return;
    float v = (float)X[(size_t)m * 64 + lane] * W[lane];
#pragma unroll
    for (int off = 32; off > 0; off >>= 1) v += __shfl_down(v, off);
    if (lane == 0) Y[m] = v;
}

__global__ __launch_bounds__(256) void agg1_kernel(const float* __restrict__ T,
                                                   const int* __restrict__ csr,
                                                   const int* __restrict__ row_off,
                                                   const float* __restrict__ r_nrm,
                                                   const float* __restrict__ bias,
                                                   float* __restrict__ Y, int N) {
    const int node = blockIdx.x * 16 + (threadIdx.x >> 4);
    const int l = threadIdx.x & 15;
    if (node >= N) return;
    const int lo = row_off[node];
    const int hi = row_off[node + 1];
    float acc = 0.f;
    for (int e = lo + l; e < hi; e += 16) acc += T[csr[e]];
#pragma unroll
    for (int m = 8; m >= 1; m >>= 1) acc += __shfl_xor(acc, m);
    if (l == 0) Y[node] = fmaf(acc, r_nrm[node], bias[0]);
}

// ---------------- host ----------------

extern "C" void kernel_launch(void* const* d_in, const int* in_sizes, int n_in,
                              void* d_out, int out_size, void* d_ws, size_t ws_size,
                              hipStream_t stream) {
    const float* in_feat = (const float*)d_in[0];
    const int* src = (const int*)d_in[1];
    const int* dst = (const int*)d_in[2];
    const float* W1 = (const float*)d_in[3];  const float* B1 = (const float*)d_in[4];
    const float* W2 = (const float*)d_in[5];  const float* B2 = (const float*)d_in[6];
    const float* W3 = (const float*)d_in[7];  const float* B3 = (const float*)d_in[8];
    const float* W4 = (const float*)d_in[9];  const float* B4 = (const float*)d_in[10];
    const float* W5 = (const float*)d_in[11]; const float* B5 = (const float*)d_in[12];
    const float* W6 = (const float*)d_in[13]; const float* B6 = (const float*)d_in[14];
    const float* W7 = (const float*)d_in[15]; const float* B7 = (const float*)d_in[16];

    const int N = in_sizes[0] / IN_F;   // 40000
    const int E = in_sizes[1];          // 640000
    float* out = (float*)d_out;

    // workspace layout (256B aligned)
    char* w = (char*)d_ws;
    auto alloc = [&](size_t bytes) { char* p = w; w += (bytes + 255) & ~(size_t)255; return p; };
    int* csr      = (int*)alloc((size_t)E * 4);
    int* row_off  = (int*)alloc((size_t)(N + 1) * 4);
    int* in_deg   = (int*)alloc((size_t)N * 4);
    int* blockSums= (int*)alloc(64 * 4);
    int* blockOffs= (int*)alloc(64 * 4);
    float* out_nrm= (float*)alloc((size_t)N * 4);
    float* in_nrm = (float*)alloc((size_t)N * 4);
    float* t7     = (float*)alloc((size_t)N * 4);
    const int dims[8] = {128, 64, 128, 128, 64, 64, 64, 1};
    unsigned short* wth[6]; unsigned short* wtl[6];
    for (int i = 0; i < 6; ++i) {
        size_t kn = (size_t)dims[i] * dims[i + 1];
        wth[i] = (unsigned short*)alloc(kn * 2);
        wtl[i] = (unsigned short*)alloc(kn * 2);
    }
    unsigned short* th = (unsigned short*)alloc((size_t)N * 128 * 2);
    unsigned short* tl = (unsigned short*)alloc((size_t)N * 128 * 2);
    _Float16* h0 = (_Float16*)alloc((size_t)N * 128 * 2);
    _Float16* h1 = (_Float16*)alloc((size_t)N * 128 * 2);
    // hist scratch aliases th+tl (2*NSHARD*NSLICE*8192*4 = 19.66MB <= 20.48MB);
    // consumed by fill2, th/tl first written at L3.
    int* scratch = (int*)th;
    (void)ws_size; (void)n_in; (void)out_size;

    const int TB = 256;
    const int NB = (N + 1023) / 1024;   // 40

    // weight split/transpose
    WPack wp;
    const float* Ws[6] = {W1, W2, W3, W4, W5, W6};
    for (int i = 0; i < 6; ++i) wp.d[i] = {Ws[i], wth[i], wtl[i], dims[i], dims[i + 1]};
    split_w_kernel<<<dim3(6, 64), TB, 0, stream>>>(wp);

    // degrees + norms + CSR (atomic-free)
    hist2_kernel<<<dim3(NSLICE, NSHARD, 2), TB, 0, stream>>>(src, dst, scratch, E);
    hist_reduce_kernel<<<(N + TB - 1) / TB, TB, 0, stream>>>(
        scratch, in_deg, out_nrm, in_nrm, N);
    scan_blk_kernel<<<NB, TB, 0, stream>>>(in_deg, blockSums, N);
    scan_top_kernel<<<1, 64, 0, stream>>>(blockSums, blockOffs, row_off, NB, N);
    scan_fill_kernel<<<NB, TB, 0, stream>>>(in_deg, blockOffs, row_off, N);
    slice_base_kernel<<<(N + TB - 1) / TB, TB, 0, stream>>>(scratch, row_off, N);
    fill2_kernel<<<dim3(NSLICE, NSHARD), TB, 0, stream>>>(src, dst, scratch, csr, E);

    const int gridN4 = (N + 3) / 4;
    const int MB = (N + 63) / 64;   // 625

    // L1: 128->64 mult-first. h0 = t1 = (x*s)@W1 ; h1 = g1 = relu(agg(t1)*r+B1)*s
    gemm_mfma_f32<128, 64><<<MB, TB, 0, stream>>>(in_feat, wth[0], wtl[0], out_nrm, h0, N);
    agg_h16<64><<<gridN4, TB, 0, stream>>>(h0, csr, row_off, in_nrm, out_nrm, B1, h1, N);

    // L2: 64->128 fused. h0 = g2 = relu(agg(g1)@W2*r+B2)*s
    fused_ag<64, 128, 0><<<MB, TB, 0, stream>>>(
        h1, csr, row_off, wth[1], wtl[1], in_nrm, out_nrm, B2, h0, nullptr, nullptr, N);

    // L3: 128->128 fused. th/tl = g3 planes (feeds L4 gemm)
    fused_ag<128, 128, 1><<<MB, TB, 0, stream>>>(
        h0, csr, row_off, wth[2], wtl[2], in_nrm, out_nrm, B3, nullptr, th, tl, N);

    // L4: 128->64 mult-first. h1 = t4 = g3@W4 ; h0 = g4 = relu(agg(t4)*r+B4)*s
    gemm_mfma<128, 64><<<MB, TB, 0, stream>>>(th, tl, wth[3], wtl[3], h1, N);
    agg_h16<64><<<gridN4, TB, 0, stream>>>(h1, csr, row_off, in_nrm, out_nrm, B4, h0, N);

    // L5: 64->64 fused. h1 = g5
    fused_ag<64, 64, 0><<<MB, TB, 0, stream>>>(
        h0, csr, row_off, wth[4], wtl[4], in_nrm, out_nrm, B5, h1, nullptr, nullptr, N);

    // L6: 64->64 fused. h0 = g6
    fused_ag<64, 64, 0><<<MB, TB, 0, stream>>>(
        h1, csr, row_off, wth[5], wtl[5], in_nrm, out_nrm, B6, h0, nullptr, nullptr, N);

    // L7: 64->1 mult-first. t7 = g6@W7 ; out = agg(t7)*r + B7
    gemv64_kernel<<<gridN4, TB, 0, stream>>>(h0, W7, t7, N);
    agg1_kernel<<<(N + 15) / 16, TB, 0, stream>>>(t7, csr, row_off, in_nrm, B7, out, N);
}

// Round 7
// 306.035 us; speedup vs baseline: 1.1369x; 1.1369x over previous
//
#include <hip/hip_runtime.h>
#include <hip/hip_bf16.h>

// GCN 7-layer forward on MI355X. R7:
//  - REVERT R6 fusion (fused_ag was latency-starved: 2500 waves x 16 serial
//    nodes vs 40000 parallel gather waves; L3 fused was 71us @13% HBM)
//  - keep L1 direct-fp32 GEMM (no split_feat round trip)
//  - NEW: all inter-layer tensors fp16; GEMMs split A fp16->bf16 hi/lo in
//    REGISTERS (lossless vs stored fp16). Deletes th/tl plane buffers:
//    ~50 MB less traffic, halves GEMM A-fetch.

#define IN_F 128
#define NSLICE 60
#define SHB 13          // 8192 nodes/shard, 32 KB LDS
#define NSHARD 5        // ceil(40000/8192)

typedef __attribute__((ext_vector_type(8))) short short8v;   // 8 bf16
typedef __attribute__((ext_vector_type(4))) float f32x4;
typedef __attribute__((ext_vector_type(8))) _Float16 half8v; // 16 B

static __device__ __forceinline__ unsigned short f2bf(float x) {
    unsigned u = __builtin_bit_cast(unsigned, x);
    unsigned r = (u + 0x7FFFu + ((u >> 16) & 1u)) >> 16;   // rn-even
    return (unsigned short)r;
}
static __device__ __forceinline__ float bf2f(unsigned short h) {
    unsigned u = ((unsigned)h) << 16;
    return __builtin_bit_cast(float, u);
}

// ---------------- LDS histogram: grid (NSLICE, NSHARD, 2) ----------------

__global__ __launch_bounds__(256) void hist2_kernel(const int* __restrict__ src,
                                                    const int* __restrict__ dst,
                                                    int* __restrict__ scratch, int E) {
    constexpr int SH = 1 << SHB;
    __shared__ int h[SH];
    const int t = threadIdx.x;
    const int b = blockIdx.x;            // edge slice
    const int s = blockIdx.y;            // node shard
    const int z = blockIdx.z;            // 0 = src (out-deg), 1 = dst (in-deg)
    const int* idx = z ? dst : src;
    for (int i = t; i < SH; i += 256) h[i] = 0;
    __syncthreads();
    const int per = (E + NSLICE - 1) / NSLICE;
    const int lo = b * per;
    const int hiE = min(lo + per, E);
    const int base = s << SHB;
    for (int e = lo + t; e < hiE; e += 256) {
        unsigned a = (unsigned)(idx[e] - base);
        if (a < (unsigned)SH) atomicAdd(&h[a], 1);
    }
    __syncthreads();
    int* so = scratch + ((size_t)((z * NSHARD + s) * NSLICE + b) << SHB);
    for (int i = t; i < SH; i += 256) so[i] = h[i];
}

__global__ void hist_reduce_kernel(const int* __restrict__ scratch,
                                   int* __restrict__ in_deg,
                                   float* __restrict__ out_nrm,
                                   float* __restrict__ in_nrm, int N) {
    constexpr int SH = 1 << SHB;
    int n = blockIdx.x * blockDim.x + threadIdx.x;
    if (n >= N) return;
    int s = n >> SHB;
    int i = n & (SH - 1);
    int od = 0, idg = 0;
    for (int b = 0; b < NSLICE; ++b) {
        od  += scratch[((size_t)((0 * NSHARD + s) * NSLICE + b) << SHB) + i];
        idg += scratch[((size_t)((1 * NSHARD + s) * NSLICE + b) << SHB) + i];
    }
    in_deg[n] = idg;
    out_nrm[n] = od  > 0 ? rsqrtf((float)od)  : 0.f;
    in_nrm[n]  = idg > 0 ? rsqrtf((float)idg) : 0.f;
}

// ---------------- multi-block exclusive scan of in_deg -> row_off ----------------

__global__ __launch_bounds__(256) void scan_blk_kernel(const int* __restrict__ deg,
                                                       int* __restrict__ blockSums, int N) {
    __shared__ int ws[4];
    const int t = threadIdx.x;
    const int base = blockIdx.x * 1024 + t * 4;
    int4 v = make_int4(0, 0, 0, 0);
    if (base + 3 < N) v = *reinterpret_cast<const int4*>(&deg[base]);
    else if (base < N) {
        v.x = deg[base];
        if (base + 1 < N) v.y = deg[base + 1];
        if (base + 2 < N) v.z = deg[base + 2];
    }
    int s = v.x + v.y + v.z + v.w;
#pragma unroll
    for (int off = 32; off > 0; off >>= 1) s += __shfl_down(s, off);
    if ((t & 63) == 0) ws[t >> 6] = s;
    __syncthreads();
    if (t == 0) blockSums[blockIdx.x] = ws[0] + ws[1] + ws[2] + ws[3];
}

__global__ __launch_bounds__(64) void scan_top_kernel(const int* __restrict__ blockSums,
                                                      int* __restrict__ blockOffs,
                                                      int* __restrict__ row_off, int NB, int N) {
    const int t = threadIdx.x;
    int orig = (t < NB) ? blockSums[t] : 0;
    int v = orig;
#pragma unroll
    for (int off = 1; off < 64; off <<= 1) {
        int u = __shfl_up(v, off);
        if (t >= off) v += u;
    }
    if (t < NB) blockOffs[t] = v - orig;
    if (t == 63) row_off[N] = v;
}

__global__ __launch_bounds__(256) void scan_fill_kernel(const int* __restrict__ deg,
                                                        const int* __restrict__ blockOffs,
                                                        int* __restrict__ row_off, int N) {
    __shared__ int wtot[4];
    const int t = threadIdx.x;
    const int lane = t & 63;
    const int wid = t >> 6;
    const int base = blockIdx.x * 1024 + t * 4;
    int4 v = make_int4(0, 0, 0, 0);
    if (base + 3 < N) v = *reinterpret_cast<const int4*>(&deg[base]);
    else if (base < N) {
        v.x = deg[base];
        if (base + 1 < N) v.y = deg[base + 1];
        if (base + 2 < N) v.z = deg[base + 2];
    }
    const int s = v.x + v.y + v.z + v.w;
    int incl = s;
#pragma unroll
    for (int off = 1; off < 64; off <<= 1) {
        int u = __shfl_up(incl, off);
        if (lane >= off) incl += u;
    }
    if (lane == 63) wtot[wid] = incl;
    __syncthreads();
    int pre = blockOffs[blockIdx.x] + incl - s;
    for (int i = 0; i < wid; ++i) pre += wtot[i];
    if (base < N) {
        int run = pre;
        row_off[base] = run; run += v.x;
        if (base + 1 < N) { row_off[base + 1] = run; run += v.y; }
        if (base + 2 < N) { row_off[base + 2] = run; run += v.z; }
        if (base + 3 < N) { row_off[base + 3] = run; }
    }
}

// per-(slice,node) dst counts -> global base positions
__global__ void slice_base_kernel(int* __restrict__ scratch,
                                  const int* __restrict__ row_off, int N) {
    constexpr int SH = 1 << SHB;
    int n = blockIdx.x * blockDim.x + threadIdx.x;
    if (n >= N) return;
    int s = n >> SHB;
    int i = n & (SH - 1);
    int run = row_off[n];
    for (int b = 0; b < NSLICE; ++b) {
        size_t off = ((size_t)((NSHARD + s) * NSLICE + b) << SHB) + i;
        int c = scratch[off];
        scratch[off] = run;
        run += c;
    }
}

// place edges using LDS cursors seeded from slice bases; no global atomics
__global__ __launch_bounds__(256) void fill2_kernel(const int* __restrict__ src,
                                                    const int* __restrict__ dst,
                                                    const int* __restrict__ scratch,
                                                    int* __restrict__ csr, int E) {
    constexpr int SH = 1 << SHB;
    __shared__ int cur[SH];
    const int t = threadIdx.x;
    const int b = blockIdx.x;   // slice
    const int s = blockIdx.y;   // shard
    const int* base = scratch + ((size_t)((NSHARD + s) * NSLICE + b) << SHB);
    for (int i = t; i < SH; i += 256) cur[i] = base[i];
    __syncthreads();
    const int per = (E + NSLICE - 1) / NSLICE;
    const int lo = b * per;
    const int hiE = min(lo + per, E);
    const int nb = s << SHB;
    for (int e = lo + t; e < hiE; e += 256) {
        unsigned a = (unsigned)(dst[e] - nb);
        if (a < (unsigned)SH) {
            int pos = atomicAdd(&cur[a], 1);
            csr[pos] = src[e];
        }
    }
}

// ---------------- weight split/transpose ----------------

struct WDesc { const float* w; unsigned short* th; unsigned short* tl; int K; int N; };
struct WPack { WDesc d[6]; };

__global__ __launch_bounds__(256) void split_w_kernel(WPack p) {
    WDesc d = p.d[blockIdx.x];
    int i = blockIdx.y * 256 + threadIdx.x;
    if (i >= d.K * d.N) return;
    int k = i / d.N, n = i - k * d.N;
    float v = d.w[i];
    unsigned short h = f2bf(v);
    d.th[(size_t)n * d.K + k] = h;
    d.tl[(size_t)n * d.K + k] = f2bf(v - bf2f(h));
}

// ---------------- L1 GEMM: fp32 input, scale+split in registers ----------------

template<int K, int NOUT>
__global__ __launch_bounds__(256) void gemm_mfma_f32(
    const float* __restrict__ X,
    const unsigned short* __restrict__ Bh, const unsigned short* __restrict__ Bl,
    const float* __restrict__ pre, _Float16* __restrict__ Y16, int M) {
    constexpr int NT = NOUT / 16;
    const int lane = threadIdx.x & 63;
    const int wv = threadIdx.x >> 6;
    const int r0 = blockIdx.x * 64 + wv * 16;
    const int arow = r0 + (lane & 15);
    const int kg = (lane >> 4) * 8;
    const float sc = pre[arow];

    f32x4 acc[NT];
#pragma unroll
    for (int n = 0; n < NT; ++n) acc[n] = (f32x4){0.f, 0.f, 0.f, 0.f};

    for (int kk = 0; kk < K; kk += 32) {
        const float* ap = &X[(size_t)arow * K + kk + kg];
        float4 v0 = *reinterpret_cast<const float4*>(ap);
        float4 v1 = *reinterpret_cast<const float4*>(ap + 4);
        float a[8] = {v0.x, v0.y, v0.z, v0.w, v1.x, v1.y, v1.z, v1.w};
        short8v a_h, a_l;
#pragma unroll
        for (int j = 0; j < 8; ++j) {
            float f = a[j] * sc;
            unsigned short hh = f2bf(f);
            a_h[j] = (short)hh;
            a_l[j] = (short)f2bf(f - bf2f(hh));
        }
#pragma unroll
        for (int n = 0; n < NT; ++n) {
            int col = n * 16 + (lane & 15);
            short8v b_h = *reinterpret_cast<const short8v*>(Bh + (size_t)col * K + kk + kg);
            short8v b_l = *reinterpret_cast<const short8v*>(Bl + (size_t)col * K + kk + kg);
            acc[n] = __builtin_amdgcn_mfma_f32_16x16x32_bf16(a_h, b_h, acc[n], 0, 0, 0);
            acc[n] = __builtin_amdgcn_mfma_f32_16x16x32_bf16(a_h, b_l, acc[n], 0, 0, 0);
            acc[n] = __builtin_amdgcn_mfma_f32_16x16x32_bf16(a_l, b_h, acc[n], 0, 0, 0);
        }
    }
    const int c0 = lane & 15;
    const int rr = r0 + (lane >> 4) * 4;
#pragma unroll
    for (int n = 0; n < NT; ++n) {
        const int col = n * 16 + c0;
#pragma unroll
        for (int j = 0; j < 4; ++j)
            Y16[(size_t)(rr + j) * NOUT + col] = (_Float16)acc[n][j];
    }
}

// ---------------- GEMM: fp16 A, split to bf16 hi/lo in registers ----------------
// epilogue: EPI ? relu(acc*r + bias)*s : plain. out fp16.

template<int K, int NOUT, bool EPI>
__global__ __launch_bounds__(256) void gemm_h16(
    const _Float16* __restrict__ X,
    const unsigned short* __restrict__ Bh, const unsigned short* __restrict__ Bl,
    const float* __restrict__ r_nrm, const float* __restrict__ s_nrm,
    const float* __restrict__ bias, _Float16* __restrict__ Y16, int M) {
    constexpr int NT = NOUT / 16;
    const int lane = threadIdx.x & 63;
    const int wv = threadIdx.x >> 6;
    const int r0 = blockIdx.x * 64 + wv * 16;
    const int arow = r0 + (lane & 15);
    const int kg = (lane >> 4) * 8;

    f32x4 acc[NT];
#pragma unroll
    for (int n = 0; n < NT; ++n) acc[n] = (f32x4){0.f, 0.f, 0.f, 0.f};

    for (int kk = 0; kk < K; kk += 32) {
        half8v av = *reinterpret_cast<const half8v*>(&X[(size_t)arow * K + kk + kg]);
        short8v a_h, a_l;
#pragma unroll
        for (int j = 0; j < 8; ++j) {
            float f = (float)av[j];
            unsigned short hh = f2bf(f);
            a_h[j] = (short)hh;
            a_l[j] = (short)f2bf(f - bf2f(hh));
        }
#pragma unroll
        for (int n = 0; n < NT; ++n) {
            int col = n * 16 + (lane & 15);
            short8v b_h = *reinterpret_cast<const short8v*>(Bh + (size_t)col * K + kk + kg);
            short8v b_l = *reinterpret_cast<const short8v*>(Bl + (size_t)col * K + kk + kg);
            acc[n] = __builtin_amdgcn_mfma_f32_16x16x32_bf16(a_h, b_h, acc[n], 0, 0, 0);
            acc[n] = __builtin_amdgcn_mfma_f32_16x16x32_bf16(a_h, b_l, acc[n], 0, 0, 0);
            acc[n] = __builtin_amdgcn_mfma_f32_16x16x32_bf16(a_l, b_h, acc[n], 0, 0, 0);
        }
    }
    const int c0 = lane & 15;
    const int rr = r0 + (lane >> 4) * 4;
#pragma unroll
    for (int n = 0; n < NT; ++n) {
        const int col = n * 16 + c0;
        const float bcol = EPI ? bias[col] : 0.f;
#pragma unroll
        for (int j = 0; j < 4; ++j) {
            const int row = rr + j;
            float y = acc[n][j];
            if (EPI) {
                y = fmaf(y, r_nrm[row], bcol);
                y = fmaxf(y, 0.f);
                y *= s_nrm[row];
            }
            Y16[(size_t)row * NOUT + col] = (_Float16)y;
        }
    }
}

// ---------------- fp16 CSR aggregation, 2x unrolled, fp16 out ----------------
// EPI ? relu(acc*r + bias)*s : plain sum.

template<int F, bool EPI>
__global__ __launch_bounds__(256) void agg_h16(
    const _Float16* __restrict__ X, const int* __restrict__ csr,
    const int* __restrict__ row_off, const float* __restrict__ r_nrm,
    const float* __restrict__ s_nrm, const float* __restrict__ bias,
    _Float16* __restrict__ Y16, int N) {
    constexpr int LPE = F / 8;
    constexpr int EPW = 64 / LPE;
    const int lane = threadIdx.x & 63;
    const int node = blockIdx.x * (blockDim.x >> 6) + (threadIdx.x >> 6);
    if (node >= N) return;
    const int g = lane / LPE;
    const int c = lane % LPE;
    const int lo = row_off[node];
    const int hi = row_off[node + 1];
    float acc[8], acc2[8];
#pragma unroll
    for (int j = 0; j < 8; ++j) { acc[j] = 0.f; acc2[j] = 0.f; }
    int e = lo + g;
    for (; e + EPW < hi; e += 2 * EPW) {
        int s0 = csr[e];
        int s1 = csr[e + EPW];
        half8v x0 = *reinterpret_cast<const half8v*>(&X[(size_t)s0 * F + c * 8]);
        half8v x1 = *reinterpret_cast<const half8v*>(&X[(size_t)s1 * F + c * 8]);
#pragma unroll
        for (int j = 0; j < 8; ++j) { acc[j] += (float)x0[j]; acc2[j] += (float)x1[j]; }
    }
    if (e < hi) {
        int s0 = csr[e];
        half8v x0 = *reinterpret_cast<const half8v*>(&X[(size_t)s0 * F + c * 8]);
#pragma unroll
        for (int j = 0; j < 8; ++j) acc[j] += (float)x0[j];
    }
#pragma unroll
    for (int j = 0; j < 8; ++j) acc[j] += acc2[j];
#pragma unroll
    for (int m = LPE; m < 64; m <<= 1) {
#pragma unroll
        for (int j = 0; j < 8; ++j) acc[j] += __shfl_xor(acc[j], m);
    }
    if (lane < LPE) {
        half8v o;
        if (EPI) {
            float rn = r_nrm[node];
            float sn = s_nrm[node];
#pragma unroll
            for (int j = 0; j < 8; ++j) {
                float y = fmaf(acc[j], rn, bias[lane * 8 + j]);
                o[j] = (_Float16)(fmaxf(y, 0.f) * sn);
            }
        } else {
#pragma unroll
            for (int j = 0; j < 8; ++j) o[j] = (_Float16)acc[j];
        }
        *reinterpret_cast<half8v*>(&Y16[(size_t)node * F + lane * 8]) = o;
    }
}

// ---------------- layer 7 ----------------

__global__ __launch_bounds__(256) void gemv64_kernel(const _Float16* __restrict__ X,
                                                     const float* __restrict__ W,
                                                     float* __restrict__ Y, int M) {
    const int lane = threadIdx.x & 63;
    const int m = blockIdx.x * (blockDim.x >> 6) + (threadIdx.x >> 6);
    if (m >= M) return;
    float v = (float)X[(size_t)m * 64 + lane] * W[lane];
#pragma unroll
    for (int off = 32; off > 0; off >>= 1) v += __shfl_down(v, off);
    if (lane == 0) Y[m] = v;
}

__global__ __launch_bounds__(256) void agg1_kernel(const float* __restrict__ T,
                                                   const int* __restrict__ csr,
                                                   const int* __restrict__ row_off,
                                                   const float* __restrict__ r_nrm,
                                                   const float* __restrict__ bias,
                                                   float* __restrict__ Y, int N) {
    const int node = blockIdx.x * 16 + (threadIdx.x >> 4);
    const int l = threadIdx.x & 15;
    if (node >= N) return;
    const int lo = row_off[node];
    const int hi = row_off[node + 1];
    float acc = 0.f;
    for (int e = lo + l; e < hi; e += 16) acc += T[csr[e]];
#pragma unroll
    for (int m = 8; m >= 1; m >>= 1) acc += __shfl_xor(acc, m);
    if (l == 0) Y[node] = fmaf(acc, r_nrm[node], bias[0]);
}

// ---------------- host ----------------

extern "C" void kernel_launch(void* const* d_in, const int* in_sizes, int n_in,
                              void* d_out, int out_size, void* d_ws, size_t ws_size,
                              hipStream_t stream) {
    const float* in_feat = (const float*)d_in[0];
    const int* src = (const int*)d_in[1];
    const int* dst = (const int*)d_in[2];
    const float* W1 = (const float*)d_in[3];  const float* B1 = (const float*)d_in[4];
    const float* W2 = (const float*)d_in[5];  const float* B2 = (const float*)d_in[6];
    const float* W3 = (const float*)d_in[7];  const float* B3 = (const float*)d_in[8];
    const float* W4 = (const float*)d_in[9];  const float* B4 = (const float*)d_in[10];
    const float* W5 = (const float*)d_in[11]; const float* B5 = (const float*)d_in[12];
    const float* W6 = (const float*)d_in[13]; const float* B6 = (const float*)d_in[14];
    const float* W7 = (const float*)d_in[15]; const float* B7 = (const float*)d_in[16];

    const int N = in_sizes[0] / IN_F;   // 40000
    const int E = in_sizes[1];          // 640000
    float* out = (float*)d_out;

    // workspace layout (256B aligned)
    char* w = (char*)d_ws;
    auto alloc = [&](size_t bytes) { char* p = w; w += (bytes + 255) & ~(size_t)255; return p; };
    int* csr      = (int*)alloc((size_t)E * 4);
    int* row_off  = (int*)alloc((size_t)(N + 1) * 4);
    int* in_deg   = (int*)alloc((size_t)N * 4);
    int* blockSums= (int*)alloc(64 * 4);
    int* blockOffs= (int*)alloc(64 * 4);
    float* out_nrm= (float*)alloc((size_t)N * 4);
    float* in_nrm = (float*)alloc((size_t)N * 4);
    float* t7     = (float*)alloc((size_t)N * 4);
    const int dims[8] = {128, 64, 128, 128, 64, 64, 64, 1};
    unsigned short* wth[6]; unsigned short* wtl[6];
    for (int i = 0; i < 6; ++i) {
        size_t kn = (size_t)dims[i] * dims[i + 1];
        wth[i] = (unsigned short*)alloc(kn * 2);
        wtl[i] = (unsigned short*)alloc(kn * 2);
    }
    _Float16* h0 = (_Float16*)alloc((size_t)N * 128 * 2);   // 10.24 MB (256-mult)
    _Float16* h1 = (_Float16*)alloc((size_t)N * 128 * 2);
    // hist scratch (2*NSHARD*NSLICE*8192*4 = 19.66 MB) aliases h0+h1 (20.48 MB
    // contiguous: N*128*2 is a 256 multiple). Consumed by fill2 before L1.
    int* scratch = (int*)h0;
    (void)ws_size; (void)n_in; (void)out_size;

    const int TB = 256;
    const int NB = (N + 1023) / 1024;   // 40

    // weight split/transpose
    WPack wp;
    const float* Ws[6] = {W1, W2, W3, W4, W5, W6};
    for (int i = 0; i < 6; ++i) wp.d[i] = {Ws[i], wth[i], wtl[i], dims[i], dims[i + 1]};
    split_w_kernel<<<dim3(6, 64), TB, 0, stream>>>(wp);

    // degrees + norms + CSR (atomic-free)
    hist2_kernel<<<dim3(NSLICE, NSHARD, 2), TB, 0, stream>>>(src, dst, scratch, E);
    hist_reduce_kernel<<<(N + TB - 1) / TB, TB, 0, stream>>>(
        scratch, in_deg, out_nrm, in_nrm, N);
    scan_blk_kernel<<<NB, TB, 0, stream>>>(in_deg, blockSums, N);
    scan_top_kernel<<<1, 64, 0, stream>>>(blockSums, blockOffs, row_off, NB, N);
    scan_fill_kernel<<<NB, TB, 0, stream>>>(in_deg, blockOffs, row_off, N);
    slice_base_kernel<<<(N + TB - 1) / TB, TB, 0, stream>>>(scratch, row_off, N);
    fill2_kernel<<<dim3(NSLICE, NSHARD), TB, 0, stream>>>(src, dst, scratch, csr, E);

    const int gridN4 = (N + 3) / 4;   // one node per wave, 4 waves/block
    const int MB = (N + 63) / 64;     // 625

    // L1: 128->64 mult-first. h0 = t1 = (x*s)@W1 ; h1 = g1 = relu(agg(t1)*r+B1)*s
    gemm_mfma_f32<128, 64><<<MB, TB, 0, stream>>>(in_feat, wth[0], wtl[0], out_nrm, h0, N);
    agg_h16<64, true><<<gridN4, TB, 0, stream>>>(h0, csr, row_off, in_nrm, out_nrm, B1, h1, N);

    // L2: 64->128 agg-first. h0 = t2 = agg(g1) ; h1 = g2 = relu(t2@W2*r+B2)*s
    agg_h16<64, false><<<gridN4, TB, 0, stream>>>(h1, csr, row_off, nullptr, nullptr, nullptr, h0, N);
    gemm_h16<64, 128, true><<<MB, TB, 0, stream>>>(h0, wth[1], wtl[1], in_nrm, out_nrm, B2, h1, N);

    // L3: 128->128 agg-first. h0 = t3 = agg(g2) ; h1 = g3
    agg_h16<128, false><<<gridN4, TB, 0, stream>>>(h1, csr, row_off, nullptr, nullptr, nullptr, h0, N);
    gemm_h16<128, 128, true><<<MB, TB, 0, stream>>>(h0, wth[2], wtl[2], in_nrm, out_nrm, B3, h1, N);

    // L4: 128->64 mult-first. h0 = t4 = g3@W4 ; h1 = g4 = relu(agg(t4)*r+B4)*s
    gemm_h16<128, 64, false><<<MB, TB, 0, stream>>>(h1, wth[3], wtl[3], nullptr, nullptr, nullptr, h0, N);
    agg_h16<64, true><<<gridN4, TB, 0, stream>>>(h0, csr, row_off, in_nrm, out_nrm, B4, h1, N);

    // L5: 64->64 agg-first. h0 = t5 = agg(g4) ; h1 = g5
    agg_h16<64, false><<<gridN4, TB, 0, stream>>>(h1, csr, row_off, nullptr, nullptr, nullptr, h0, N);
    gemm_h16<64, 64, true><<<MB, TB, 0, stream>>>(h0, wth[4], wtl[4], in_nrm, out_nrm, B5, h1, N);

    // L6: 64->64 agg-first. h0 = t6 = agg(g5) ; h1 = g6
    agg_h16<64, false><<<gridN4, TB, 0, stream>>>(h1, csr, row_off, nullptr, nullptr, nullptr, h0, N);
    gemm_h16<64, 64, true><<<MB, TB, 0, stream>>>(h0, wth[5], wtl[5], in_nrm, out_nrm, B6, h1, N);

    // L7: 64->1 mult-first. t7 = g6@W7 ; out = agg(t7)*r + B7
    gemv64_kernel<<<gridN4, TB, 0, stream>>>(h1, W7, t7, N);
    agg1_kernel<<<(N + 15) / 16, TB, 0, stream>>>(t7, csr, row_off, in_nrm, B7, out, N);
}